// Round 4
// baseline (584.567 us; speedup 1.0000x reference)
//
#include <hip/hip_runtime.h>
#include <stdint.h>

// GraphAttentionLayer kernel set for MI355X (gfx950). Round 4.
// Pipeline (big-ws path):
//   K1 conv_wt : W[k][c] fp32 -> WT[c][k] bf16 (LDS-tiled transpose)
//   K2 wh_gemm : Wh = h@W + bW via bf16 MFMA -> WhT[c][i] bf16
//                + fused epilogue: raw scores s1 = Wh@a1, s2 = Wh@a2
//   K3 w_k     : w[i][j] = adj ? exp(lrelu(s1_i+s2_j+b1+b2)) : 0 (bf16),
//                dinv[i] = 1/rowsum  (HBM-streaming, grid 8192)
//   K4 pv_gemm : out = (w @ WhT^T) * dinv — MFMA GEMM, 32x128 tile, BK=128,
//                grid 1024 -> 4 blocks/CU (LDS 40960B x4 = exactly 160KiB),
//                XOR-16 LDS swizzle, XCD-aware map (4 c-blocks of a w
//                row-stripe share an XCD L2 -> w from HBM once).
//                R2 showed the old 64x128/2-blocks-per-CU variant was
//                latency-bound (MfmaUtil 17.8%): barrier vmcnt-drain ~900cy
//                vs 77cy MFMA. 4-way block interleave covers the drain.

#define NN 8192
#define DD 512

typedef __attribute__((ext_vector_type(8))) short short8;
typedef __attribute__((ext_vector_type(4))) float f32x4;
typedef __attribute__((ext_vector_type(4))) float float4v;
typedef __attribute__((ext_vector_type(4))) unsigned short ushort4v;

__device__ __forceinline__ uint16_t f2bf(float f) {
  union { float f; uint32_t u; } v; v.f = f;
  uint32_t u = v.u;
  u += 0x7fffu + ((u >> 16) & 1u);   // round-nearest-even
  return (uint16_t)(u >> 16);
}
__device__ __forceinline__ float bf2f(uint16_t b) {
  union { uint32_t u; float f; } v; v.u = ((uint32_t)b) << 16;
  return v.f;
}

__device__ __forceinline__ void async_copy16(uint16_t* lds, const uint16_t* g) {
  __builtin_amdgcn_global_load_lds(
      (const __attribute__((address_space(1))) uint32_t*)g,
      (__attribute__((address_space(3))) uint32_t*)lds, 16, 0, 0);
}

// ---- K1: tiled transpose+convert W (512x512) ----
__global__ __launch_bounds__(256) void conv_wt(const float* __restrict__ W,
                                               uint16_t* __restrict__ WT) {
  __shared__ float ts[64][65];
  int tid = threadIdx.x;
  int kt = (blockIdx.x >> 3) * 64, ct = (blockIdx.x & 7) * 64;
  #pragma unroll
  for (int it = 0; it < 4; ++it) {
    int idx = it * 256 + tid;
    int r = idx >> 4, q = idx & 15;
    float4v v = *(const float4v*)(W + (size_t)(kt + r) * 512 + ct + q * 4);
    ts[r][q * 4 + 0] = v.x; ts[r][q * 4 + 1] = v.y;
    ts[r][q * 4 + 2] = v.z; ts[r][q * 4 + 3] = v.w;
  }
  __syncthreads();
  #pragma unroll
  for (int it = 0; it < 4; ++it) {
    int idx = it * 256 + tid;
    int c = idx >> 4, q = idx & 15;
    ushort4v p;
    p.x = f2bf(ts[q * 4 + 0][c]); p.y = f2bf(ts[q * 4 + 1][c]);
    p.z = f2bf(ts[q * 4 + 2][c]); p.w = f2bf(ts[q * 4 + 3][c]);
    *(ushort4v*)(WT + (size_t)(ct + c) * 512 + kt + q * 4) = p;
  }
}

// ---- K2: Wh GEMM -> WhT[c][i] bf16, fused raw scores s1,s2 ----
__global__ __launch_bounds__(512) void wh_gemm(const float* __restrict__ h,
                                               const uint16_t* __restrict__ WT,
                                               const float* __restrict__ bW,
                                               const float* __restrict__ a1,
                                               const float* __restrict__ a2,
                                               uint16_t* __restrict__ WhT,
                                               float* __restrict__ s1g,
                                               float* __restrict__ s2g) {
  __shared__ __align__(16) uint16_t At[32 * 32];
  __shared__ __align__(16) uint16_t Bt[512 * 32];
  __shared__ float s1loc[32], s2loc[32];
  int tid = threadIdx.x;
  int wave = tid >> 6, lane = tid & 63;
  int l15 = lane & 15, quad = lane >> 4;
  int i0 = blockIdx.x * 32;
  if (tid < 32) { s1loc[tid] = 0.f; s2loc[tid] = 0.f; }
  f32x4 acc[2][4] = {};
  for (int k0 = 0; k0 < 512; k0 += 32) {
    if (tid < 256) {
      int r = tid >> 3, ks = (tid & 7) * 4;
      float4v hv = *(const float4v*)(h + (size_t)(i0 + r) * 512 + k0 + ks);
      ushort4v p;
      p.x = f2bf(hv.x); p.y = f2bf(hv.y); p.z = f2bf(hv.z); p.w = f2bf(hv.w);
      *(ushort4v*)&At[r * 32 + ks] = p;
    }
    #pragma unroll
    for (int rr = 0; rr < 4; ++rr) {
      int idx = rr * 512 + tid;
      int c = idx >> 2, q = idx & 3;
      async_copy16(&Bt[idx * 8], WT + c * 512 + k0 + q * 8);
    }
    __syncthreads();
    short8 a0 = *(const short8*)&At[l15 * 32 + quad * 8];
    short8 a1f = *(const short8*)&At[(l15 + 16) * 32 + quad * 8];
    #pragma unroll
    for (int nt = 0; nt < 4; ++nt) {
      int c = wave * 64 + nt * 16 + l15;
      short8 b = *(const short8*)&Bt[c * 32 + quad * 8];
      acc[0][nt] = __builtin_amdgcn_mfma_f32_16x16x32_bf16(a0, b, acc[0][nt], 0, 0, 0);
      acc[1][nt] = __builtin_amdgcn_mfma_f32_16x16x32_bf16(a1f, b, acc[1][nt], 0, 0, 0);
    }
    __syncthreads();
  }
  #pragma unroll
  for (int mt = 0; mt < 2; ++mt) {
    int ib = i0 + mt * 16 + quad * 4;
    float r1[4] = {0.f, 0.f, 0.f, 0.f};
    float r2[4] = {0.f, 0.f, 0.f, 0.f};
    #pragma unroll
    for (int nt = 0; nt < 4; ++nt) {
      int c = wave * 64 + nt * 16 + l15;
      float bias = bW[c];
      float a1c = a1[c], a2c = a2[c];
      float v0 = acc[mt][nt].x + bias;
      float v1 = acc[mt][nt].y + bias;
      float v2 = acc[mt][nt].z + bias;
      float v3 = acc[mt][nt].w + bias;
      ushort4v p;
      p.x = f2bf(v0); p.y = f2bf(v1); p.z = f2bf(v2); p.w = f2bf(v3);
      *(ushort4v*)&WhT[(size_t)c * 8192 + ib] = p;
      r1[0] = fmaf(v0, a1c, r1[0]); r1[1] = fmaf(v1, a1c, r1[1]);
      r1[2] = fmaf(v2, a1c, r1[2]); r1[3] = fmaf(v3, a1c, r1[3]);
      r2[0] = fmaf(v0, a2c, r2[0]); r2[1] = fmaf(v1, a2c, r2[1]);
      r2[2] = fmaf(v2, a2c, r2[2]); r2[3] = fmaf(v3, a2c, r2[3]);
    }
    #pragma unroll
    for (int v = 0; v < 4; ++v) {
      int row = mt * 16 + quad * 4 + v;
      atomicAdd(&s1loc[row], r1[v]);
      atomicAdd(&s2loc[row], r2[v]);
    }
  }
  __syncthreads();
  if (tid < 32) {
    s1g[i0 + tid] = s1loc[tid];
    s2g[i0 + tid] = s2loc[tid];
  }
}

// ---- K3: materialize w (bf16) + dinv. One row per block, 256 thr. ----
__global__ __launch_bounds__(256) void w_k(const int* __restrict__ adj,
                                           const float* __restrict__ s1,
                                           const float* __restrict__ s2,
                                           const float* __restrict__ b1,
                                           const float* __restrict__ b2,
                                           uint16_t* __restrict__ w,
                                           float* __restrict__ dinv) {
  __shared__ float wsum[4];
  int i = blockIdx.x;
  int tid = threadIdx.x;
  float base = s1[i] + b1[0] + b2[0];
  const int* arow = adj + (size_t)i * 8192;
  uint16_t* wrow = w + (size_t)i * 8192;
  float sum = 0.f;
  #pragma unroll
  for (int it = 0; it < 8; ++it) {
    int j = it * 1024 + tid * 4;
    int4 av = *(const int4*)(arow + j);
    float4v sv = *(const float4v*)(s2 + j);
    float e, wv;
    ushort4v p;
    e = base + sv.x; e = fmaxf(e, 0.2f * e);
    wv = (av.x > 0) ? __expf(e) : 0.f; p.x = f2bf(wv); sum += bf2f(p.x);
    e = base + sv.y; e = fmaxf(e, 0.2f * e);
    wv = (av.y > 0) ? __expf(e) : 0.f; p.y = f2bf(wv); sum += bf2f(p.y);
    e = base + sv.z; e = fmaxf(e, 0.2f * e);
    wv = (av.z > 0) ? __expf(e) : 0.f; p.z = f2bf(wv); sum += bf2f(p.z);
    e = base + sv.w; e = fmaxf(e, 0.2f * e);
    wv = (av.w > 0) ? __expf(e) : 0.f; p.w = f2bf(wv); sum += bf2f(p.w);
    *(ushort4v*)(wrow + j) = p;
  }
  #pragma unroll
  for (int o = 32; o > 0; o >>= 1) sum += __shfl_down(sum, o);
  if ((tid & 63) == 0) wsum[tid >> 6] = sum;
  __syncthreads();
  if (tid == 0) dinv[i] = 1.0f / (wsum[0] + wsum[1] + wsum[2] + wsum[3]);
}

// ---- K4: out = (w @ WhT^T) * dinv. 32x128 tile, BK=128, 512 thr. ----
// grid 1024 (rb=blockIdx&255, cb=blockIdx>>8): 4 blocks/CU; the 4 blocks
// sharing a w row-stripe are 256 apart == same XCD (%8) -> w HBM once.
// LDS = 8192(A) + 32768(B) = 40960 B; x4 blocks = exactly 160 KiB.
__global__ __launch_bounds__(512, 8) void pv_gemm(const uint16_t* __restrict__ w,
                                                  const uint16_t* __restrict__ WhT,
                                                  const float* __restrict__ dinv,
                                                  float* __restrict__ out) {
  __shared__ __align__(16) uint16_t At[32 * 128];    // 8 KB, XOR-16 swizzled
  __shared__ __align__(16) uint16_t Bt[128 * 128];   // 32 KB, XOR-16 swizzled
  int tid = threadIdx.x;
  int wave = tid >> 6, lane = tid & 63;
  int l15 = lane & 15, quad = lane >> 4;
  int rb = blockIdx.x & 255, cb = blockIdx.x >> 8;
  int i0 = rb * 32, c0 = cb * 128;
  f32x4 acc[2] = {};
  // A staging indices: 512 chunks of 16B, 1 per thread
  int ar = tid >> 4, ap = tid & 15;
  int asc = ap ^ (ar & 15);
  const uint16_t* aptr = w + (size_t)(i0 + ar) * 8192 + asc * 8;
  for (int j0 = 0; j0 < 8192; j0 += 128) {
    // A: 32 rows x 128 j = 8 KB. LDS dst linear in tid (global_load_lds
    // constraint); source chunk XOR-swizzled: LDS pos p of row r holds
    // global chunk p^(r&15).
    async_copy16(&At[tid * 8], aptr + j0);
    // B: 128 rows x 128 j = 32 KB = 2048 chunks, 4/thread
    #pragma unroll
    for (int it = 0; it < 4; ++it) {
      int idx = it * 512 + tid;
      int r = idx >> 4, p = idx & 15;
      int sc = p ^ (r & 15);
      async_copy16(&Bt[idx * 8], WhT + (size_t)(c0 + r) * 8192 + j0 + sc * 8);
    }
    __syncthreads();
    int brow = wave * 16 + l15;
    #pragma unroll
    for (int ks = 0; ks < 4; ++ks) {
      int ch = ks * 4 + quad;
      short8 b = *(const short8*)&Bt[brow * 128 + ((ch ^ (brow & 15)) * 8)];
      #pragma unroll
      for (int rt = 0; rt < 2; ++rt) {
        int arow = rt * 16 + l15;
        short8 a = *(const short8*)&At[arow * 128 + ((ch ^ (arow & 15)) * 8)];
        acc[rt] = __builtin_amdgcn_mfma_f32_16x16x32_bf16(a, b, acc[rt], 0, 0, 0);
      }
    }
    __syncthreads();
  }
  #pragma unroll
  for (int rt = 0; rt < 2; ++rt) {
    #pragma unroll
    for (int v = 0; v < 4; ++v) {
      int rloc = rt * 16 + quad * 4 + v;
      float dv = dinv[i0 + rloc];
      out[(size_t)(i0 + rloc) * 512 + c0 + wave * 16 + l15] = acc[rt][v] * dv;
    }
  }
}

// ================= fallback path (small workspace) =================
__global__ __launch_bounds__(512) void attn_k(const int* __restrict__ adj,
                                              const float* __restrict__ s1,
                                              const float* __restrict__ s2,
                                              const float* __restrict__ b1,
                                              const float* __restrict__ b2,
                                              const uint16_t* __restrict__ WhT,
                                              float* __restrict__ out) {
  __shared__ __align__(16) uint16_t At[32 * 32];
  __shared__ __align__(16) uint16_t Bt[512 * 32];
  __shared__ float dred[512];
  __shared__ float dinv[32];
  int tid = threadIdx.x;
  int wave = tid >> 6, lane = tid & 63;
  int l15 = lane & 15, quad = lane >> 4;
  int i0 = blockIdx.x * 32;
  int wr = tid >> 4;
  int wc = (tid & 15) * 2;
  float s1v = s1[i0 + wr] + b1[0] + b2[0];
  float dpart = 0.f;
  f32x4 acc[2][4] = {};
  const int* adjrow = adj + (size_t)(i0 + wr) * 8192 + wc;
  for (int j0 = 0; j0 < 8192; j0 += 32) {
    int2 av = *(const int2*)(adjrow + j0);
    float2 s2v = *(const float2*)(s2 + j0 + wc);
    float e0 = s1v + s2v.x; e0 = fmaxf(e0, 0.2f * e0);
    float e1 = s1v + s2v.y; e1 = fmaxf(e1, 0.2f * e1);
    float w0 = (av.x > 0) ? __expf(e0) : 0.f;
    float w1 = (av.y > 0) ? __expf(e1) : 0.f;
    dpart += w0 + w1;
    uint32_t packed = (uint32_t)f2bf(w0) | ((uint32_t)f2bf(w1) << 16);
    *(uint32_t*)&At[wr * 32 + wc] = packed;
    #pragma unroll
    for (int rr = 0; rr < 4; ++rr) {
      int idx = rr * 512 + tid;
      int c = idx >> 2, q = idx & 3;
      async_copy16(&Bt[idx * 8], WhT + (size_t)c * 8192 + j0 + q * 8);
    }
    __syncthreads();
    short8 a0 = *(const short8*)&At[l15 * 32 + quad * 8];
    short8 a1f = *(const short8*)&At[(l15 + 16) * 32 + quad * 8];
    #pragma unroll
    for (int nt = 0; nt < 4; ++nt) {
      short8 b = *(const short8*)&Bt[(wave * 64 + nt * 16 + l15) * 32 + quad * 8];
      acc[0][nt] = __builtin_amdgcn_mfma_f32_16x16x32_bf16(a0, b, acc[0][nt], 0, 0, 0);
      acc[1][nt] = __builtin_amdgcn_mfma_f32_16x16x32_bf16(a1f, b, acc[1][nt], 0, 0, 0);
    }
    __syncthreads();
  }
  dred[tid] = dpart;
  __syncthreads();
  if (tid < 32) {
    float s = 0.f;
    #pragma unroll
    for (int q = 0; q < 16; ++q) s += dred[tid * 16 + q];
    dinv[tid] = 1.0f / s;
  }
  __syncthreads();
  #pragma unroll
  for (int mt = 0; mt < 2; ++mt) {
    #pragma unroll
    for (int nt = 0; nt < 4; ++nt) {
      int c = wave * 64 + nt * 16 + l15;
      #pragma unroll
      for (int v = 0; v < 4; ++v) {
        int row = mt * 16 + quad * 4 + v;
        out[(size_t)(i0 + row) * 512 + c] = acc[mt][nt][v] * dinv[row];
      }
    }
  }
}

extern "C" void kernel_launch(void* const* d_in, const int* in_sizes, int n_in,
                              void* d_out, int out_size, void* d_ws, size_t ws_size,
                              hipStream_t stream) {
  const float* h   = (const float*)d_in[0];
  const int*   adj = (const int*)d_in[1];
  const float* W   = (const float*)d_in[2];
  const float* bW  = (const float*)d_in[3];
  const float* a1  = (const float*)d_in[4];
  const float* b1  = (const float*)d_in[5];
  const float* a2  = (const float*)d_in[6];
  const float* b2  = (const float*)d_in[7];
  float* out = (float*)d_out;
  char* ws = (char*)d_ws;

  const size_t NEED = 143228928ULL;
  if (ws_size >= NEED) {
    uint16_t* w   = (uint16_t*)(ws);                  // 134217728
    uint16_t* WhT = (uint16_t*)(ws + 134217728);      // 8388608
    uint16_t* WT  = (uint16_t*)(ws + 142606336);      // 524288
    float* s1     = (float*)(ws + 143130624);         // 32768
    float* s2     = (float*)(ws + 143163392);         // 32768
    float* dinv   = (float*)(ws + 143196160);         // 32768

    conv_wt<<<64, 256, 0, stream>>>(W, WT);
    wh_gemm<<<256, 512, 0, stream>>>(h, WT, bW, a1, a2, WhT, s1, s2);
    w_k<<<8192, 256, 0, stream>>>(adj, s1, s2, b1, b2, w, dinv);
    pv_gemm<<<1024, 512, 0, stream>>>(w, WhT, dinv, out);
  } else {
    uint16_t* WhT = (uint16_t*)(ws);
    uint16_t* WT  = (uint16_t*)(ws + 8388608);
    float* s1     = (float*)(ws + 8912896);
    float* s2     = (float*)(ws + 8945664);

    conv_wt<<<64, 256, 0, stream>>>(W, WT);
    wh_gemm<<<256, 512, 0, stream>>>(h, WT, bW, a1, a2, WhT, s1, s2);
    attn_k<<<256, 512, 0, stream>>>(adj, s1, s2, b1, b2, WhT, out);
  }
}

// Round 6
// 548.722 us; speedup vs baseline: 1.0653x; 1.0653x over previous
//
#include <hip/hip_runtime.h>
#include <stdint.h>

// GraphAttentionLayer kernel set for MI355X (gfx950). Round 6.
// Pipeline:
//   K1 conv_wt : W[k][c] fp32 -> WT[c][k] bf16 (LDS-tiled transpose)
//   K2 wh_gemm : Wh = h@W + bW via bf16 MFMA -> WhT[c][i] bf16
//                + fused epilogue: raw scores s1 = Wh@a1, s2 = Wh@a2
//   K3 attn2   : FULLY FUSED masked-softmax @ Wh. Per block: 32 rows x 256
//                cols of out. j-loop BJ=128: w-tile computed IN REGISTERS
//                (adj int4 prefetch + __expf) -> LDS A-operand; WhT tile
//                staged via global_load_lds(16B); 128 MFMA/block/iter.
// R5 bug: A-tile swizzled write used (p ^ wr) with wr in [0,32) -> OOB LDS
// write into Bt for wr>=16 (NaN). Fix: (p ^ (wr & 15)) — read side already
// masks to 15.

#define NN 8192
#define DD 512

typedef __attribute__((ext_vector_type(8))) short short8;
typedef __attribute__((ext_vector_type(4))) float f32x4;
typedef __attribute__((ext_vector_type(4))) float float4v;
typedef __attribute__((ext_vector_type(4))) unsigned short ushort4v;

__device__ __forceinline__ uint16_t f2bf(float f) {
  union { float f; uint32_t u; } v; v.f = f;
  uint32_t u = v.u;
  u += 0x7fffu + ((u >> 16) & 1u);   // round-nearest-even
  return (uint16_t)(u >> 16);
}
__device__ __forceinline__ float bf2f(uint16_t b) {
  union { uint32_t u; float f; } v; v.u = ((uint32_t)b) << 16;
  return v.f;
}

__device__ __forceinline__ void async_copy16(uint16_t* lds, const uint16_t* g) {
  __builtin_amdgcn_global_load_lds(
      (const __attribute__((address_space(1))) uint32_t*)g,
      (__attribute__((address_space(3))) uint32_t*)lds, 16, 0, 0);
}

// ---- K1: tiled transpose+convert W (512x512) ----
__global__ __launch_bounds__(256) void conv_wt(const float* __restrict__ W,
                                               uint16_t* __restrict__ WT) {
  __shared__ float ts[64][65];
  int tid = threadIdx.x;
  int kt = (blockIdx.x >> 3) * 64, ct = (blockIdx.x & 7) * 64;
  #pragma unroll
  for (int it = 0; it < 4; ++it) {
    int idx = it * 256 + tid;
    int r = idx >> 4, q = idx & 15;
    float4v v = *(const float4v*)(W + (size_t)(kt + r) * 512 + ct + q * 4);
    ts[r][q * 4 + 0] = v.x; ts[r][q * 4 + 1] = v.y;
    ts[r][q * 4 + 2] = v.z; ts[r][q * 4 + 3] = v.w;
  }
  __syncthreads();
  #pragma unroll
  for (int it = 0; it < 4; ++it) {
    int idx = it * 256 + tid;
    int c = idx >> 4, q = idx & 15;
    ushort4v p;
    p.x = f2bf(ts[q * 4 + 0][c]); p.y = f2bf(ts[q * 4 + 1][c]);
    p.z = f2bf(ts[q * 4 + 2][c]); p.w = f2bf(ts[q * 4 + 3][c]);
    *(ushort4v*)(WT + (size_t)(ct + c) * 512 + kt + q * 4) = p;
  }
}

// ---- K2: Wh GEMM -> WhT[c][i] bf16, fused raw scores s1,s2 ----
__global__ __launch_bounds__(512) void wh_gemm(const float* __restrict__ h,
                                               const uint16_t* __restrict__ WT,
                                               const float* __restrict__ bW,
                                               const float* __restrict__ a1,
                                               const float* __restrict__ a2,
                                               uint16_t* __restrict__ WhT,
                                               float* __restrict__ s1g,
                                               float* __restrict__ s2g) {
  __shared__ __align__(16) uint16_t At[32 * 32];
  __shared__ __align__(16) uint16_t Bt[512 * 32];
  __shared__ float s1loc[32], s2loc[32];
  int tid = threadIdx.x;
  int wave = tid >> 6, lane = tid & 63;
  int l15 = lane & 15, quad = lane >> 4;
  int i0 = blockIdx.x * 32;
  if (tid < 32) { s1loc[tid] = 0.f; s2loc[tid] = 0.f; }
  f32x4 acc[2][4] = {};
  for (int k0 = 0; k0 < 512; k0 += 32) {
    if (tid < 256) {
      int r = tid >> 3, ks = (tid & 7) * 4;
      float4v hv = *(const float4v*)(h + (size_t)(i0 + r) * 512 + k0 + ks);
      ushort4v p;
      p.x = f2bf(hv.x); p.y = f2bf(hv.y); p.z = f2bf(hv.z); p.w = f2bf(hv.w);
      *(ushort4v*)&At[r * 32 + ks] = p;
    }
    #pragma unroll
    for (int rr = 0; rr < 4; ++rr) {
      int idx = rr * 512 + tid;
      int c = idx >> 2, q = idx & 3;
      async_copy16(&Bt[idx * 8], WT + c * 512 + k0 + q * 8);
    }
    __syncthreads();
    short8 a0 = *(const short8*)&At[l15 * 32 + quad * 8];
    short8 a1f = *(const short8*)&At[(l15 + 16) * 32 + quad * 8];
    #pragma unroll
    for (int nt = 0; nt < 4; ++nt) {
      int c = wave * 64 + nt * 16 + l15;
      short8 b = *(const short8*)&Bt[c * 32 + quad * 8];
      acc[0][nt] = __builtin_amdgcn_mfma_f32_16x16x32_bf16(a0, b, acc[0][nt], 0, 0, 0);
      acc[1][nt] = __builtin_amdgcn_mfma_f32_16x16x32_bf16(a1f, b, acc[1][nt], 0, 0, 0);
    }
    __syncthreads();
  }
  #pragma unroll
  for (int mt = 0; mt < 2; ++mt) {
    int ib = i0 + mt * 16 + quad * 4;
    float r1[4] = {0.f, 0.f, 0.f, 0.f};
    float r2[4] = {0.f, 0.f, 0.f, 0.f};
    #pragma unroll
    for (int nt = 0; nt < 4; ++nt) {
      int c = wave * 64 + nt * 16 + l15;
      float bias = bW[c];
      float a1c = a1[c], a2c = a2[c];
      float v0 = acc[mt][nt].x + bias;
      float v1 = acc[mt][nt].y + bias;
      float v2 = acc[mt][nt].z + bias;
      float v3 = acc[mt][nt].w + bias;
      ushort4v p;
      p.x = f2bf(v0); p.y = f2bf(v1); p.z = f2bf(v2); p.w = f2bf(v3);
      *(ushort4v*)&WhT[(size_t)c * 8192 + ib] = p;
      r1[0] = fmaf(v0, a1c, r1[0]); r1[1] = fmaf(v1, a1c, r1[1]);
      r1[2] = fmaf(v2, a1c, r1[2]); r1[3] = fmaf(v3, a1c, r1[3]);
      r2[0] = fmaf(v0, a2c, r2[0]); r2[1] = fmaf(v1, a2c, r2[1]);
      r2[2] = fmaf(v2, a2c, r2[2]); r2[3] = fmaf(v3, a2c, r2[3]);
    }
    #pragma unroll
    for (int v = 0; v < 4; ++v) {
      int row = mt * 16 + quad * 4 + v;
      atomicAdd(&s1loc[row], r1[v]);
      atomicAdd(&s2loc[row], r2[v]);
    }
  }
  __syncthreads();
  if (tid < 32) {
    s1g[i0 + tid] = s1loc[tid];
    s2g[i0 + tid] = s2loc[tid];
  }
}

// ---- K3: fused masked-softmax attention @ Wh ----
// Block = 32 out-rows x 256 out-cols (cb half). 512 thr = 8 waves.
// Block map: rb=(x&7)|((x>>4)<<3), cb=(x>>3)&1 -> the 2 cb-blocks of a
// row-stripe are 8 apart == same XCD (%8) -> adj from HBM once.
// LDS: Bt 64KB + At 8KB + dred 2KB -> 2 blocks/CU.
__global__ __launch_bounds__(512, 4) void attn2(const int* __restrict__ adj,
                                                const float* __restrict__ s1,
                                                const float* __restrict__ s2,
                                                const float* __restrict__ b1,
                                                const float* __restrict__ b2,
                                                const uint16_t* __restrict__ WhT,
                                                float* __restrict__ out) {
  __shared__ __align__(16) uint16_t At[32 * 128];    // 8 KB, XOR-16 swizzled
  __shared__ __align__(16) uint16_t Bt[256 * 128];   // 64 KB, XOR-16 swizzled
  __shared__ float dred[512];
  __shared__ float dloc[32];
  int tid = threadIdx.x;
  int wave = tid >> 6, lane = tid & 63;
  int l15 = lane & 15, quad = lane >> 4;
  int x = blockIdx.x;
  int cb = (x >> 3) & 1;
  int rb = (x & 7) | ((x >> 4) << 3);
  int i0 = rb * 32, c0 = cb * 256;
  // w-generation role: row wr (0..31), chunk p (0..15) of 8 cols
  int wr = tid >> 4, p = tid & 15;
  float s1v = s1[i0 + wr] + b1[0] + b2[0];
  const int* adjp = adj + (size_t)(i0 + wr) * 8192 + p * 8;
  const float* s2p = s2 + p * 8;
  // R5 fix: swizzle on (wr & 15), matching the read side's (row & 15)
  uint16_t* awp = &At[wr * 128 + ((p ^ (wr & 15)) * 8)];
  float dpart = 0.f;
  f32x4 acc[2][2] = {};
  // adj register prefetch (1 iteration ahead)
  int4 av0 = *(const int4*)(adjp);
  int4 av1 = *(const int4*)(adjp + 4);
  for (int j0 = 0; j0 < 8192; j0 += 128) {
    // B staging: 256 rows x 128 j = 64 KB = 4096 chunks, 8/thread
    #pragma unroll
    for (int it = 0; it < 8; ++it) {
      int idx = it * 512 + tid;
      int r = idx >> 4, pp = idx & 15;
      int sc = pp ^ (r & 15);
      async_copy16(&Bt[idx * 8], WhT + (size_t)(c0 + r) * 8192 + j0 + sc * 8);
    }
    // prefetch next adj tile into regs (wrap-read on last iter, harmless)
    int jn = (j0 + 128) & 8191;
    int4 nv0 = *(const int4*)(adjp + jn);
    int4 nv1 = *(const int4*)(adjp + jn + 4);
    // compute my 8 w values (cols j0 + p*8 + 0..7)
    float4v sv0 = *(const float4v*)(s2p + j0);
    float4v sv1 = *(const float4v*)(s2p + j0 + 4);
    short8 pk;
    float e, wv;
    uint16_t b;
    e = s1v + sv0.x; e = fmaxf(e, 0.2f * e);
    wv = (av0.x > 0) ? __expf(e) : 0.f; b = f2bf(wv); pk[0] = (short)b; dpart += bf2f(b);
    e = s1v + sv0.y; e = fmaxf(e, 0.2f * e);
    wv = (av0.y > 0) ? __expf(e) : 0.f; b = f2bf(wv); pk[1] = (short)b; dpart += bf2f(b);
    e = s1v + sv0.z; e = fmaxf(e, 0.2f * e);
    wv = (av0.z > 0) ? __expf(e) : 0.f; b = f2bf(wv); pk[2] = (short)b; dpart += bf2f(b);
    e = s1v + sv0.w; e = fmaxf(e, 0.2f * e);
    wv = (av0.w > 0) ? __expf(e) : 0.f; b = f2bf(wv); pk[3] = (short)b; dpart += bf2f(b);
    e = s1v + sv1.x; e = fmaxf(e, 0.2f * e);
    wv = (av1.x > 0) ? __expf(e) : 0.f; b = f2bf(wv); pk[4] = (short)b; dpart += bf2f(b);
    e = s1v + sv1.y; e = fmaxf(e, 0.2f * e);
    wv = (av1.y > 0) ? __expf(e) : 0.f; b = f2bf(wv); pk[5] = (short)b; dpart += bf2f(b);
    e = s1v + sv1.z; e = fmaxf(e, 0.2f * e);
    wv = (av1.z > 0) ? __expf(e) : 0.f; b = f2bf(wv); pk[6] = (short)b; dpart += bf2f(b);
    e = s1v + sv1.w; e = fmaxf(e, 0.2f * e);
    wv = (av1.w > 0) ? __expf(e) : 0.f; b = f2bf(wv); pk[7] = (short)b; dpart += bf2f(b);
    *(short8*)awp = pk;            // ds_write_b128
    av0 = nv0; av1 = nv1;
    __syncthreads();               // drains async B + A ds_writes
    // MFMA: 4 k-chunks x (2m x 2n) = 16 per wave
    int brow0 = wave * 32 + l15;
    int brow1 = brow0 + 16;
    #pragma unroll
    for (int ks = 0; ks < 4; ++ks) {
      int ch = ks * 4 + quad;
      short8 b0 = *(const short8*)&Bt[brow0 * 128 + ((ch ^ l15) * 8)];
      short8 b1f = *(const short8*)&Bt[brow1 * 128 + ((ch ^ l15) * 8)];
      short8 am0 = *(const short8*)&At[l15 * 128 + ((ch ^ l15) * 8)];
      short8 am1 = *(const short8*)&At[(l15 + 16) * 128 + ((ch ^ l15) * 8)];
      acc[0][0] = __builtin_amdgcn_mfma_f32_16x16x32_bf16(am0, b0, acc[0][0], 0, 0, 0);
      acc[0][1] = __builtin_amdgcn_mfma_f32_16x16x32_bf16(am0, b1f, acc[0][1], 0, 0, 0);
      acc[1][0] = __builtin_amdgcn_mfma_f32_16x16x32_bf16(am1, b0, acc[1][0], 0, 0, 0);
      acc[1][1] = __builtin_amdgcn_mfma_f32_16x16x32_bf16(am1, b1f, acc[1][1], 0, 0, 0);
    }
    __syncthreads();
  }
  // denominator reduce: 16 partials per row
  dred[tid] = dpart;
  __syncthreads();
  if (tid < 32) {
    float s = 0.f;
    #pragma unroll
    for (int q = 0; q < 16; ++q) s += dred[tid * 16 + q];
    dloc[tid] = 1.0f / s;
  }
  __syncthreads();
  // epilogue
  #pragma unroll
  for (int mt = 0; mt < 2; ++mt) {
    #pragma unroll
    for (int nt = 0; nt < 2; ++nt) {
      int c = c0 + wave * 32 + nt * 16 + l15;
      #pragma unroll
      for (int v = 0; v < 4; ++v) {
        int row = mt * 16 + quad * 4 + v;
        out[(size_t)(i0 + row) * 512 + c] = acc[mt][nt][v] * dloc[row];
      }
    }
  }
}

extern "C" void kernel_launch(void* const* d_in, const int* in_sizes, int n_in,
                              void* d_out, int out_size, void* d_ws, size_t ws_size,
                              hipStream_t stream) {
  const float* h   = (const float*)d_in[0];
  const int*   adj = (const int*)d_in[1];
  const float* W   = (const float*)d_in[2];
  const float* bW  = (const float*)d_in[3];
  const float* a1  = (const float*)d_in[4];
  const float* b1  = (const float*)d_in[5];
  const float* a2  = (const float*)d_in[6];
  const float* b2  = (const float*)d_in[7];
  float* out = (float*)d_out;
  char* ws = (char*)d_ws;

  uint16_t* WhT = (uint16_t*)(ws);               // 8388608 B
  uint16_t* WT  = (uint16_t*)(ws + 8388608);     // 524288 B
  float* s1     = (float*)(ws + 8912896);        // 32768 B
  float* s2     = (float*)(ws + 8945664);        // 32768 B

  conv_wt<<<64, 256, 0, stream>>>(W, WT);
  wh_gemm<<<256, 512, 0, stream>>>(h, WT, bW, a1, a2, WhT, s1, s2);
  attn2<<<512, 512, 0, stream>>>(adj, s1, s2, b1, b2, WhT, out);
}